// Round 7
// baseline (196.532 us; speedup 1.0000x reference)
//
#include <hip/hip_runtime.h>
#include <math.h>

// Shapes (compile-time)
#define BB 16
#define LL 28
#define RR 64
#define DD 512
#define NROLE 1024          // role blocks: (r, 64-wide d range, 256-wide e half)
#define NEVT  256           // evt blocks: (b, 32-wide d range)

// ---------------------------------------------------------------------------
// Kernel A (fused, single accumulator, atomics into 32 KB L2-resident buffer):
//  blockIdx%5 != 4 -> role block rid: phase 1 builds G[64 rows][16 b] in 4 KB
//    LDS, ONE barrier; phase 2 streams its 64 KB WRT slice (8-deep register
//    float4 double-buffer), G via uniform ds_read_b128 broadcasts. Each wave
//    owns a disjoint b-quarter (4 float4 accs) -> 16 atomicAdds/lane at end.
//  blockIdx%5 == 4 -> evt block: batched float4 WTT loads, 2-stream LDS
//    combine, atomicAdds into the same accumulator (div+evt summed; MLP
//    multiplies by 0.5).
// ---------------------------------------------------------------------------
__global__ void __launch_bounds__(256, 4) kernel_a(
    const float* __restrict__ logits,   // [B,L,R]
    const float* __restrict__ arg,      // [B,L,D]
    const float* __restrict__ WRT,      // [R,D,D]
    const float* __restrict__ WTT,      // [E,D,D]
    const float* __restrict__ evt_emb,  // [B,1,D]
    const int*   __restrict__ evt_type, // [B]
    float* __restrict__ acc_buf)        // [B,D] zero-initialized
{
    __shared__ float smem[1024];        // 4 KB
    const int t   = threadIdx.x;
    const int q   = blockIdx.x / 5;
    const int rem = blockIdx.x - 5 * q;

    if (rem == 4) {
        // ---------------- evt transform ----------------
        const int cid = q;              // [0,256)
        const int b  = cid >> 4;
        const int dc = cid & 15;
        const int d0 = dc * 32;
        const int ty = evt_type[b];
        const float* Wt = WTT + (size_t)ty * DD * DD;
        const int e4 = t & 127;
        const int s  = t >> 7;          // 2 d-streams
        float4 a = {0.f, 0.f, 0.f, 0.f};
#pragma unroll
        for (int db = 0; db < 32; db += 16) {
            float  em[8];
            float4 w[8];
#pragma unroll
            for (int i = 0; i < 8; ++i) {
                const int d = d0 + db + s + 2 * i;
                em[i] = evt_emb[b * DD + d];                       // uniform
                w[i]  = ((const float4*)(Wt + (size_t)d * DD))[e4];
            }
#pragma unroll
            for (int i = 0; i < 8; ++i) {
                a.x = fmaf(em[i], w[i].x, a.x);
                a.y = fmaf(em[i], w[i].y, a.y);
                a.z = fmaf(em[i], w[i].z, a.z);
                a.w = fmaf(em[i], w[i].w, a.w);
            }
        }
        // combine 2 streams via LDS (consecutive-f4 layout: conflict-free)
        float4* sm4 = (float4*)smem;
        if (s == 1) sm4[e4] = a;
        __syncthreads();
        if (s == 0) {
            const float4 q4 = sm4[e4];
            a.x += q4.x; a.y += q4.y; a.z += q4.z; a.w += q4.w;
            float* dst = acc_buf + b * DD + e4 * 4;
            atomicAdd(dst + 0, a.x);
            atomicAdd(dst + 1, a.y);
            atomicAdd(dst + 2, a.z);
            atomicAdd(dst + 3, a.w);
        }
        return;
    }

    // -------- role block: (r, d-range d0, e-half eh), k = 64 --------
    const int rid = q * 4 + rem;        // [0,1024)
    const int r   = rid >> 4;
    const int d0  = ((rid >> 1) & 7) * 64;
    const int eh  = rid & 1;

    // WRT slice: rows d0..d0+63, columns eh*256..eh*256+255 (64 f4 per row)
    const float4* Wp = (const float4*)(WRT + ((size_t)r * DD + d0) * DD + eh * 256);

    const int e4 = t & 63;              // float4 e-column within the half
    const int bq = t >> 6;              // b-quarter (waves own disjoint 4 b's)

    // Prefetch WRT batch 0 (k-rows 0..7) BEFORE phase 1.
    float4 w[8];
#pragma unroll
    for (int i = 0; i < 8; ++i)
        w[i] = Wp[(size_t)i * 128 + e4];

    // Phase 1: G[row][b], row = d-local in [0,64), b in [0,16).
    {
        const int b  = t >> 4;
        const int d4 = t & 15;          // float4 d-group (coalesced arg)
        const float4* ap = (const float4*)(arg) + (size_t)(b * LL) * 128 + (d0 >> 2) + d4;
        const float*  lp = logits + (b * LL) * RR + r;
        float4 g = {0.f, 0.f, 0.f, 0.f};
#pragma unroll 7
        for (int l = 0; l < LL; ++l) {
            const float4 av = ap[(size_t)l * 128];
            const float lg = lp[l * RR];
            g.x = fmaf(lg, av.x, g.x);
            g.y = fmaf(lg, av.y, g.y);
            g.z = fmaf(lg, av.z, g.z);
            g.w = fmaf(lg, av.w, g.w);
        }
        smem[(4 * d4 + 0) * 16 + b] = g.x;
        smem[(4 * d4 + 1) * 16 + b] = g.y;
        smem[(4 * d4 + 2) * 16 + b] = g.z;
        smem[(4 * d4 + 3) * 16 + b] = g.w;
    }
    __syncthreads();                    // the ONLY barrier in the role path

    // Phase 2: 8 batches of 8 k-rows, register double-buffered.
    float4 acc0 = {0.f,0.f,0.f,0.f}, acc1 = {0.f,0.f,0.f,0.f};
    float4 acc2 = {0.f,0.f,0.f,0.f}, acc3 = {0.f,0.f,0.f,0.f};

    const float* G = smem;              // [64][16]
    for (int kb = 0; kb < 8; ++kb) {
        const int kbn = (kb + 1) & 7;   // wraps harmlessly on last iter
        float4 wn[8];
#pragma unroll
        for (int i = 0; i < 8; ++i)
            wn[i] = Wp[(size_t)(kbn * 8 + i) * 128 + e4];
#pragma unroll
        for (int i = 0; i < 8; ++i) {
            const int kk = kb * 8 + i;
            // this wave's 4 b-values: one uniform b128 broadcast
            const float4 ga = ((const float4*)(G + kk * 16 + 4 * bq))[0];
            acc0.x = fmaf(ga.x, w[i].x, acc0.x); acc0.y = fmaf(ga.x, w[i].y, acc0.y);
            acc0.z = fmaf(ga.x, w[i].z, acc0.z); acc0.w = fmaf(ga.x, w[i].w, acc0.w);
            acc1.x = fmaf(ga.y, w[i].x, acc1.x); acc1.y = fmaf(ga.y, w[i].y, acc1.y);
            acc1.z = fmaf(ga.y, w[i].z, acc1.z); acc1.w = fmaf(ga.y, w[i].w, acc1.w);
            acc2.x = fmaf(ga.z, w[i].x, acc2.x); acc2.y = fmaf(ga.z, w[i].y, acc2.y);
            acc2.z = fmaf(ga.z, w[i].z, acc2.z); acc2.w = fmaf(ga.z, w[i].w, acc2.w);
            acc3.x = fmaf(ga.w, w[i].x, acc3.x); acc3.y = fmaf(ga.w, w[i].y, acc3.y);
            acc3.z = fmaf(ga.w, w[i].z, acc3.z); acc3.w = fmaf(ga.w, w[i].w, acc3.w);
        }
#pragma unroll
        for (int i = 0; i < 8; ++i) w[i] = wn[i];
    }

    // Accumulate into the shared 32 KB L2-resident buffer.
    float* dst = acc_buf + (4 * bq) * DD + eh * 256 + e4 * 4;
    atomicAdd(dst + 0,          acc0.x); atomicAdd(dst + 1,          acc0.y);
    atomicAdd(dst + 2,          acc0.z); atomicAdd(dst + 3,          acc0.w);
    atomicAdd(dst + DD + 0,     acc1.x); atomicAdd(dst + DD + 1,     acc1.y);
    atomicAdd(dst + DD + 2,     acc1.z); atomicAdd(dst + DD + 3,     acc1.w);
    atomicAdd(dst + 2 * DD + 0, acc2.x); atomicAdd(dst + 2 * DD + 1, acc2.y);
    atomicAdd(dst + 2 * DD + 2, acc2.z); atomicAdd(dst + 2 * DD + 3, acc2.w);
    atomicAdd(dst + 3 * DD + 0, acc3.x); atomicAdd(dst + 3 * DD + 1, acc3.y);
    atomicAdd(dst + 3 * DD + 2, acc3.z); atomicAdd(dst + 3 * DD + 3, acc3.w);
}

// ---------------------------------------------------------------------------
// MLP: graph = acc*0.5 ; h = relu(graph@w1+b1) ; out = sigmoid(h@w2+b2)
// ---------------------------------------------------------------------------
__global__ void __launch_bounds__(256) kernel_mlp(
    const float* __restrict__ acc_buf,  // [B,D]  (div+evt summed)
    const float* __restrict__ w1,       // [D,64]
    const float* __restrict__ b1,       // [64]
    const float* __restrict__ w2,       // [64,1]
    const float* __restrict__ b2,       // [1]
    float* __restrict__ out)            // [B,1]
{
    __shared__ float hred[256];
    const int b  = blockIdx.x;
    const int t  = threadIdx.x;
    const int j  = t & 63;
    const int dq = t >> 6;
    float hp = 0.f;
#pragma unroll 8
    for (int i = 0; i < 128; ++i) {
        const int d = dq * 128 + i;
        const float g = acc_buf[b * DD + d] * 0.5f;   // uniform
        hp = fmaf(g, w1[d * 64 + j], hp);
    }
    hred[t] = hp;
    __syncthreads();
    if (t < 64) {
        float h = b1[j] + hred[j] + hred[64 + j] + hred[128 + j] + hred[192 + j];
        h = fmaxf(h, 0.f);
        float v = h * w2[j];
#pragma unroll
        for (int off = 32; off > 0; off >>= 1) v += __shfl_down(v, off, 64);
        if (j == 0) out[b] = 1.f / (1.f + expf(-(v + b2[0])));
    }
}

// ---------------------------------------------------------------------------
extern "C" void kernel_launch(void* const* d_in, const int* in_sizes, int n_in,
                              void* d_out, int out_size, void* d_ws, size_t ws_size,
                              hipStream_t stream) {
    const float* logits   = (const float*)d_in[0];
    const float* evt_emb  = (const float*)d_in[1];
    const float* arg_emb  = (const float*)d_in[2];
    // d_in[3] arg_padding_num cancels algebraically; unused
    const int*   evt_type = (const int*)d_in[4];
    const float* WRT      = (const float*)d_in[5];
    const float* WTT      = (const float*)d_in[6];
    const float* w1       = (const float*)d_in[7];
    const float* b1       = (const float*)d_in[8];
    const float* w2       = (const float*)d_in[9];
    const float* b2       = (const float*)d_in[10];
    float* out = (float*)d_out;

    float* acc_buf = (float*)d_ws;      // B*D floats = 32 KB

    hipMemsetAsync(acc_buf, 0, BB * DD * sizeof(float), stream);

    hipLaunchKernelGGL(kernel_a, dim3(NROLE + NEVT), dim3(256), 0, stream,
                       logits, arg_emb, WRT, WTT, evt_emb, evt_type, acc_buf);
    hipLaunchKernelGGL(kernel_mlp, dim3(BB), dim3(256), 0, stream,
                       acc_buf, w1, b1, w2, b2, out);
}

// Round 8
// 159.254 us; speedup vs baseline: 1.2341x; 1.2341x over previous
//
#include <hip/hip_runtime.h>
#include <math.h>

// Shapes (compile-time)
#define BB 16
#define LL 28
#define RR 64
#define DD 512
#define KK (RR * DD)        // 32768
#define NROLE 512           // role blocks: (e-half, k-chunk of 128 rows)
#define NEVT  256           // evt blocks: (b, 32-wide d range)

// ---------------------------------------------------------------------------
// Kernel G: Gt[k][b] = sum_l logits[b,l,r]*arg[b,l,d],  k = r*512+d.
// grid = (b,r-pair) = 512 blocks x 512 threads (thread = d). logits loads are
// block-uniform (s_load); arg loads coalesced; arg value reused for both r.
// ---------------------------------------------------------------------------
__global__ void __launch_bounds__(512) kernel_g(
    const float* __restrict__ logits,   // [B,L,R]
    const float* __restrict__ arg,      // [B,L,D]
    float* __restrict__ Gt)             // [K,16]
{
    const int b  = blockIdx.x >> 5;
    const int rp = blockIdx.x & 31;
    const int r0 = rp * 2;
    const int d  = threadIdx.x;
    const float* lp  = logits + (b * LL) * RR;          // + l*RR + r (uniform)
    const float* apb = arg + (size_t)(b * LL) * DD + d; // coalesced
    float g0 = 0.f, g1 = 0.f;
#pragma unroll
    for (int l = 0; l < LL; ++l) {
        const float av = apb[(size_t)l * DD];
        g0 = fmaf(lp[l * RR + r0],     av, g0);
        g1 = fmaf(lp[l * RR + r0 + 1], av, g1);
    }
    Gt[((size_t)r0 * DD + d) * 16 + b]       = g0;
    Gt[((size_t)(r0 + 1) * DD + d) * 16 + b] = g1;
}

// ---------------------------------------------------------------------------
// Kernel A:
//  blocks [0,512): role. Block = (k-chunk c of 128 W-rows, e-half eh).
//    Wave (bh,rg) owns b-half bh, rows rg*64..+63. Hot loop per row:
//    1 coalesced b128 W load + 1 s_load_dwordx8 of Gt row (wave-uniform via
//    readfirstlane -> scalar cache) + 32 v_fma. NO LDS / barriers in loop.
//    One conflict-free 16 KB LDS combine (rg pairs) at end; partial
//    [16][128]f4 stored to part[c].
//  blocks [512,768): evt transform (unchanged R6 scheme) -> evt_part.
// ---------------------------------------------------------------------------
__global__ void __launch_bounds__(256, 3) kernel_a(
    const float* __restrict__ WRT,      // [R,D,D] = flat [K,512]
    const float* __restrict__ WTT,      // [E,D,D]
    const float* __restrict__ evt_emb,  // [B,1,D]
    const int*   __restrict__ evt_type, // [B]
    const float* __restrict__ Gt,       // [K,16]
    float* __restrict__ part,           // [256][16][128] float4-granular
    float* __restrict__ evt_part)       // [B*16][128] float4-granular
{
    __shared__ float4 comb[1024];       // 16 KB
    const int t = threadIdx.x;

    if (blockIdx.x >= NROLE) {
        // ---------------- evt transform ----------------
        const int cid = blockIdx.x - NROLE;
        const int b  = cid >> 4;
        const int dc = cid & 15;
        const int d0 = dc * 32;
        const int ty = evt_type[b];
        const float* Wt = WTT + (size_t)ty * DD * DD;
        const int e4 = t & 127;
        const int s  = t >> 7;          // 2 d-streams
        float4 a = {0.f, 0.f, 0.f, 0.f};
#pragma unroll
        for (int db = 0; db < 32; db += 16) {
            float  em[8];
            float4 w[8];
#pragma unroll
            for (int i = 0; i < 8; ++i) {
                const int d = d0 + db + s + 2 * i;
                em[i] = evt_emb[b * DD + d];                       // uniform
                w[i]  = ((const float4*)(Wt + (size_t)d * DD))[e4];
            }
#pragma unroll
            for (int i = 0; i < 8; ++i) {
                a.x = fmaf(em[i], w[i].x, a.x);
                a.y = fmaf(em[i], w[i].y, a.y);
                a.z = fmaf(em[i], w[i].z, a.z);
                a.w = fmaf(em[i], w[i].w, a.w);
            }
        }
        if (s == 1) comb[e4] = a;
        __syncthreads();
        if (s == 0) {
            const float4 q4 = comb[e4];
            a.x += q4.x; a.y += q4.y; a.z += q4.z; a.w += q4.w;
            ((float4*)evt_part)[(size_t)cid * 128 + e4] = a;
        }
        return;
    }

    // ---------------- role GEMM chunk ----------------
    const int c  = blockIdx.x >> 1;     // k-chunk [0,256): rows c*128..+127
    const int eh = blockIdx.x & 1;      // e-half
    const int e4 = t & 63;              // f4 column within half
    const int wid = __builtin_amdgcn_readfirstlane(t >> 6);
    const int bh = wid & 1;             // b-half
    const int rg = wid >> 1;            // row-group
    const int k0 = __builtin_amdgcn_readfirstlane(c * 128 + rg * 64);

    const float4* Wp = (const float4*)WRT + (size_t)k0 * 128 + eh * 64 + e4;
    const float*  Gp = Gt + (size_t)k0 * 16 + bh * 8;

    float4 acc[8];
#pragma unroll
    for (int j = 0; j < 8; ++j) acc[j] = make_float4(0.f, 0.f, 0.f, 0.f);

    // Hot loop: 64 rows; all loads independent; no LDS, no barriers.
#pragma unroll 8
    for (int i = 0; i < 64; ++i) {
        const float4 w = Wp[(size_t)i * 128];    // coalesced 16 B/lane
        const float* gr = Gp + i * 16;           // wave-uniform -> s_load
        const float g0 = gr[0], g1 = gr[1], g2 = gr[2], g3 = gr[3];
        const float g4 = gr[4], g5 = gr[5], g6 = gr[6], g7 = gr[7];
        acc[0].x = fmaf(g0, w.x, acc[0].x); acc[0].y = fmaf(g0, w.y, acc[0].y);
        acc[0].z = fmaf(g0, w.z, acc[0].z); acc[0].w = fmaf(g0, w.w, acc[0].w);
        acc[1].x = fmaf(g1, w.x, acc[1].x); acc[1].y = fmaf(g1, w.y, acc[1].y);
        acc[1].z = fmaf(g1, w.z, acc[1].z); acc[1].w = fmaf(g1, w.w, acc[1].w);
        acc[2].x = fmaf(g2, w.x, acc[2].x); acc[2].y = fmaf(g2, w.y, acc[2].y);
        acc[2].z = fmaf(g2, w.z, acc[2].z); acc[2].w = fmaf(g2, w.w, acc[2].w);
        acc[3].x = fmaf(g3, w.x, acc[3].x); acc[3].y = fmaf(g3, w.y, acc[3].y);
        acc[3].z = fmaf(g3, w.z, acc[3].z); acc[3].w = fmaf(g3, w.w, acc[3].w);
        acc[4].x = fmaf(g4, w.x, acc[4].x); acc[4].y = fmaf(g4, w.y, acc[4].y);
        acc[4].z = fmaf(g4, w.z, acc[4].z); acc[4].w = fmaf(g4, w.w, acc[4].w);
        acc[5].x = fmaf(g5, w.x, acc[5].x); acc[5].y = fmaf(g5, w.y, acc[5].y);
        acc[5].z = fmaf(g5, w.z, acc[5].z); acc[5].w = fmaf(g5, w.w, acc[5].w);
        acc[6].x = fmaf(g6, w.x, acc[6].x); acc[6].y = fmaf(g6, w.y, acc[6].y);
        acc[6].z = fmaf(g6, w.z, acc[6].z); acc[6].w = fmaf(g6, w.w, acc[6].w);
        acc[7].x = fmaf(g7, w.x, acc[7].x); acc[7].y = fmaf(g7, w.y, acc[7].y);
        acc[7].z = fmaf(g7, w.z, acc[7].z); acc[7].w = fmaf(g7, w.w, acc[7].w);
    }

    // Combine rg=1 into rg=0 via LDS (b128, contiguous per wave: conflict-free).
    if (rg == 1) {
#pragma unroll
        for (int j = 0; j < 8; ++j) comb[(bh * 8 + j) * 64 + e4] = acc[j];
    }
    __syncthreads();
    if (rg == 0) {
        float4* po = (float4*)part + (size_t)c * 2048;   // [16][128] f4
#pragma unroll
        for (int j = 0; j < 8; ++j) {
            const float4 q = comb[(bh * 8 + j) * 64 + e4];
            acc[j].x += q.x; acc[j].y += q.y; acc[j].z += q.z; acc[j].w += q.w;
            po[(bh * 8 + j) * 128 + eh * 64 + e4] = acc[j];
        }
    }
}

// ---------------------------------------------------------------------------
// Reduce (plain stores):
//  blocks [0,128): div_acc — block owns 16 f4 outputs; 16 p-groups of 16;
//    LDS combine.
//  blocks [128,136): evt_acc — sum 16 d-chunks per (b, e4).
// ---------------------------------------------------------------------------
__global__ void __launch_bounds__(256) kernel_reduce(
    const float* __restrict__ part,     // [256][2048] float4-granular
    const float* __restrict__ evt_part, // [256][128] float4-granular
    float* __restrict__ div_acc,        // [8192]
    float* __restrict__ evt_acc)        // [8192]
{
    const int t = threadIdx.x;
    if (blockIdx.x < 128) {
        __shared__ float4 sred[256];
        const int oo = t & 15;
        const int pg = t >> 4;          // 16 groups x 16 chunks
        const int o4 = blockIdx.x * 16 + oo;
        const float4* p4 = (const float4*)part;
        float4 s = {0.f, 0.f, 0.f, 0.f};
#pragma unroll 4
        for (int i = 0; i < 16; ++i) {
            const int p = pg * 16 + i;
            const float4 v = p4[(size_t)p * 2048 + o4];
            s.x += v.x; s.y += v.y; s.z += v.z; s.w += v.w;
        }
        sred[pg * 16 + oo] = s;
        __syncthreads();
        if (t < 16) {
            float4 tot = sred[t];
#pragma unroll
            for (int g = 1; g < 16; ++g) {
                const float4 v = sred[g * 16 + t];
                tot.x += v.x; tot.y += v.y; tot.z += v.z; tot.w += v.w;
            }
            ((float4*)div_acc)[blockIdx.x * 16 + t] = tot;
        }
    } else {
        const int o4 = (blockIdx.x - 128) * 256 + t;   // [0,2048)
        const int b  = o4 >> 7;
        const int el = o4 & 127;
        const float4* e4p = (const float4*)evt_part;
        float4 s = {0.f, 0.f, 0.f, 0.f};
#pragma unroll
        for (int dc = 0; dc < 16; ++dc) {
            const float4 v = e4p[(size_t)(b * 16 + dc) * 128 + el];
            s.x += v.x; s.y += v.y; s.z += v.z; s.w += v.w;
        }
        ((float4*)evt_acc)[o4] = s;
    }
}

// ---------------------------------------------------------------------------
// MLP: graph=(div+evt)/2 ; h=relu(graph@w1+b1) ; out=sigmoid(h@w2+b2)
// ---------------------------------------------------------------------------
__global__ void __launch_bounds__(256) kernel_mlp(
    const float* __restrict__ div_acc,  // [B,D]
    const float* __restrict__ evt_acc,  // [B,D]
    const float* __restrict__ w1,       // [D,64]
    const float* __restrict__ b1,       // [64]
    const float* __restrict__ w2,       // [64,1]
    const float* __restrict__ b2,       // [1]
    float* __restrict__ out)            // [B,1]
{
    __shared__ float hred[256];
    const int b  = blockIdx.x;
    const int t  = threadIdx.x;
    const int j  = t & 63;
    const int dq = t >> 6;
    float hp = 0.f;
#pragma unroll 8
    for (int i = 0; i < 128; ++i) {
        const int d = dq * 128 + i;
        const float g = (div_acc[b * DD + d] + evt_acc[b * DD + d]) * 0.5f;
        hp = fmaf(g, w1[d * 64 + j], hp);
    }
    hred[t] = hp;
    __syncthreads();
    if (t < 64) {
        float h = b1[j] + hred[j] + hred[64 + j] + hred[128 + j] + hred[192 + j];
        h = fmaxf(h, 0.f);
        float v = h * w2[j];
#pragma unroll
        for (int off = 32; off > 0; off >>= 1) v += __shfl_down(v, off, 64);
        if (j == 0) out[b] = 1.f / (1.f + expf(-(v + b2[0])));
    }
}

// ---------------------------------------------------------------------------
extern "C" void kernel_launch(void* const* d_in, const int* in_sizes, int n_in,
                              void* d_out, int out_size, void* d_ws, size_t ws_size,
                              hipStream_t stream) {
    const float* logits   = (const float*)d_in[0];
    const float* evt_emb  = (const float*)d_in[1];
    const float* arg_emb  = (const float*)d_in[2];
    // d_in[3] arg_padding_num cancels algebraically; unused
    const int*   evt_type = (const int*)d_in[4];
    const float* WRT      = (const float*)d_in[5];
    const float* WTT      = (const float*)d_in[6];
    const float* w1       = (const float*)d_in[7];
    const float* b1       = (const float*)d_in[8];
    const float* w2       = (const float*)d_in[9];
    const float* b2       = (const float*)d_in[10];
    float* out = (float*)d_out;

    float* Gt       = (float*)d_ws;                      // K*16 floats = 2 MB
    float* part     = Gt + (size_t)KK * 16;              // 256*8192 = 8.39 MB
    float* evt_part = part + (size_t)256 * 8192;         // 512 KB
    float* div_acc  = evt_part + NEVT * DD;              // 32 KB
    float* evt_acc  = div_acc + BB * DD;                 // 32 KB

    hipLaunchKernelGGL(kernel_g, dim3(512), dim3(512), 0, stream,
                       logits, arg_emb, Gt);
    hipLaunchKernelGGL(kernel_a, dim3(NROLE + NEVT), dim3(256), 0, stream,
                       WRT, WTT, evt_emb, evt_type, Gt, part, evt_part);
    hipLaunchKernelGGL(kernel_reduce, dim3(136), dim3(256), 0, stream,
                       part, evt_part, div_acc, evt_acc);
    hipLaunchKernelGGL(kernel_mlp, dim3(BB), dim3(256), 0, stream,
                       div_acc, evt_acc, w1, b1, w2, b2, out);
}